// Round 1
// baseline (546.805 us; speedup 1.0000x reference)
//
#include <hip/hip_runtime.h>

// Radon forward projection (parallel beam), 512x512 image, 512 angles,
// 736 detectors x 736 samples, bilinear interpolation.
// Outputs (flat, concatenated): sino [1,512,736] then reco [1,512,512].

namespace {
constexpr int H = 512, W = 512, NA = 512, ND = 736, NS = 736;
constexpr int SINO_SIZE = NA * ND;     // 376832
constexpr int IMG_SIZE = H * W;        // 262144
}

// img = x + reco into workspace; also pass-through reco into output slot 1.
__global__ void prep_stage(const float* __restrict__ x, const float* __restrict__ reco,
                           float* __restrict__ img, float* __restrict__ reco_out) {
    int i = blockIdx.x * blockDim.x + threadIdx.x;
    if (i < IMG_SIZE) {
        float r = reco[i];
        img[i] = x[i] + r;
        reco_out[i] = r;
    }
}

// Fallback (tiny ws): only the reco pass-through.
__global__ void prep_copy(const float* __restrict__ reco, float* __restrict__ reco_out) {
    int i = blockIdx.x * blockDim.x + threadIdx.x;
    if (i < IMG_SIZE) reco_out[i] = reco[i];
}

// One thread per (angle, detector); loop over the NS ray samples.
// FUSED=true reads x+reco per tap (no workspace); FUSED=false reads staged img.
template<bool FUSED>
__global__ __launch_bounds__(256) void proj_kernel(const float* __restrict__ A,
                                                   const float* __restrict__ B,
                                                   const float* __restrict__ angles,
                                                   float* __restrict__ sino) {
    const int d = blockIdx.x * blockDim.x + threadIdx.x;
    const int a = blockIdx.y;
    if (d >= ND) return;

    const float theta = angles[a];
    float si, c;
    sincosf(theta, &si, &c);

    const float cx = (W - 1) * 0.5f;
    const float cy = (H - 1) * 0.5f;
    const float s  = (float)d - (ND - 1) * 0.5f;
    const float bx = fmaf(s, c, cx);   // px = bx - t*si
    const float by = fmaf(s, si, cy);  // py = by + t*c
    const float t0 = -(float)(NS - 1) * 0.5f;

    auto load = [&](int idx) -> float {
        return FUSED ? (A[idx] + B[idx]) : A[idx];
    };

    float acc = 0.f;
    for (int k = 0; k < NS; ++k) {
        const float t  = t0 + (float)k;
        const float px = fmaf(t, -si, bx);
        const float py = fmaf(t,  c,  by);
        const float x0f = floorf(px);
        const float y0f = floorf(py);
        const float fx = px - x0f;
        const float fy = py - y0f;
        const int ix = (int)x0f;
        const int iy = (int)y0f;

        float v = 0.f;
        if (ix >= 0 && iy >= 0 && ix < W - 1 && iy < H - 1) {
            // Interior fast path: whole 2x2 footprint in-bounds.
            const int idx = iy * W + ix;
            const float v00 = load(idx);
            const float v01 = load(idx + 1);
            const float v10 = load(idx + W);
            const float v11 = load(idx + W + 1);
            const float top = fmaf(fx, v01 - v00, v00);
            const float bot = fmaf(fx, v11 - v10, v10);
            v = fmaf(fy, bot - top, top);
        } else if (ix >= -1 && iy >= -1 && ix <= W - 1 && iy <= H - 1) {
            // Edge path: per-tap validity, zero outside.
            auto tap = [&](int yi, int xi) -> float {
                if (xi < 0 || xi >= W || yi < 0 || yi >= H) return 0.f;
                return load(yi * W + xi);
            };
            const float v00 = tap(iy, ix);
            const float v01 = tap(iy, ix + 1);
            const float v10 = tap(iy + 1, ix);
            const float v11 = tap(iy + 1, ix + 1);
            const float top = fmaf(fx, v01 - v00, v00);
            const float bot = fmaf(fx, v11 - v10, v10);
            v = fmaf(fy, bot - top, top);
        }
        acc += v;
    }
    sino[a * ND + d] = acc;  // STEP = 1.0
}

extern "C" void kernel_launch(void* const* d_in, const int* in_sizes, int n_in,
                              void* d_out, int out_size, void* d_ws, size_t ws_size,
                              hipStream_t stream) {
    const float* x      = (const float*)d_in[0];
    const float* reco   = (const float*)d_in[1];
    const float* angles = (const float*)d_in[2];
    float* sino     = (float*)d_out;
    float* reco_out = sino + SINO_SIZE;

    const dim3 pb(256), pg((IMG_SIZE + 255) / 256);
    const dim3 jb(256), jg((ND + 255) / 256, NA);

    if (ws_size >= (size_t)IMG_SIZE * sizeof(float)) {
        float* img = (float*)d_ws;
        prep_stage<<<pg, pb, 0, stream>>>(x, reco, img, reco_out);
        proj_kernel<false><<<jg, jb, 0, stream>>>(img, nullptr, angles, sino);
    } else {
        prep_copy<<<pg, pb, 0, stream>>>(reco, reco_out);
        proj_kernel<true><<<jg, jb, 0, stream>>>(x, reco, angles, sino);
    }
}

// Round 2
// 425.473 us; speedup vs baseline: 1.2852x; 1.2852x over previous
//
#include <hip/hip_runtime.h>
#include <hip/hip_fp16.h>

// Radon forward projection (parallel beam), 512x512 image, 512 angles,
// 736 detectors x 736 samples, bilinear interpolation.
// Outputs (flat, concatenated): sino [1,512,736] then reco [1,512,512].
//
// R2: (a) exact per-ray t-clipping (valid samples per angle = 512^2 exactly,
//     vs 736^2 sampled -> 2.07x work cut), (b) fp16 image + transposed copy,
//     per-angle orientation so lane-step along contiguous dim >= 0.707 px,
//     (c) 4x unrolled interior loop, 4 accumulators, no bounds checks.

namespace {
constexpr int H = 512, W = 512, NA = 512, ND = 736, NS = 736;
constexpr int SINO_SIZE = NA * ND;
constexpr int IMG_SIZE = H * W;
}

// Build fp16 img = x + reco, fp16 transposed copy (LDS-tiled), reco pass-through.
__global__ __launch_bounds__(1024) void prep_stage(const float* __restrict__ x,
                                                   const float* __restrict__ reco,
                                                   __half* __restrict__ img,
                                                   __half* __restrict__ imgT,
                                                   float* __restrict__ reco_out) {
    __shared__ float tile[32][33];
    const int tx = threadIdx.x, ty = threadIdx.y;
    const int col = blockIdx.x * 32 + tx;
    const int row = blockIdx.y * 32 + ty;
    const int i = row * W + col;
    const float r = reco[i];
    const float v = x[i] + r;
    reco_out[i] = r;
    img[i] = __float2half(v);
    tile[ty][tx] = v;
    __syncthreads();
    // imgT[c][r] = img[r][c]; coalesced store of column-block
    const int trow = blockIdx.x * 32 + ty;
    const int tcol = blockIdx.y * 32 + tx;
    imgT[trow * W + tcol] = __float2half(tile[tx][ty]);
}

// Per-dim k-range for p0 + k*inc in [lo, hi].
__device__ inline void range1(float p0, float inc, float lo, float hi,
                              float& klo, float& khi) {
    if (inc > 1e-6f)       { klo = (lo - p0) / inc; khi = (hi - p0) / inc; }
    else if (inc < -1e-6f) { klo = (hi - p0) / inc; khi = (lo - p0) / inc; }
    else if (p0 >= lo && p0 <= hi) { klo = -1e9f; khi = 1e9f; }
    else                   { klo = 1e9f;  khi = -1e9f; }
}

__global__ __launch_bounds__(256) void proj_kernel(const __half* __restrict__ img,
                                                   const __half* __restrict__ imgT,
                                                   const float* __restrict__ angles,
                                                   float* __restrict__ sino) {
    const int d = blockIdx.x * blockDim.x + threadIdx.x;
    const int a = blockIdx.y;
    if (d >= ND) return;

    float si, c;
    sincosf(angles[a], &si, &c);

    const float cx = (W - 1) * 0.5f, cy = (H - 1) * 0.5f;
    const float s  = (float)d - (ND - 1) * 0.5f;
    const float bx = fmaf(s, c, cx);    // px = bx - t*si
    const float by = fmaf(s, si, cy);   // py = by + t*c

    // Orientation: fast dim = contiguous dim of chosen layout. Pick the one
    // where |increment per detector| (= lane step) is maximal (>= 0.707).
    const __half* base;
    float f0, fi, s0, sli;
    if (fabsf(c) >= fabsf(si)) { base = img;  f0 = bx; fi = -si; s0 = by; sli = c;  }
    else                       { base = imgT; f0 = by; fi = c;   s0 = bx; sli = -si; }

    const float t0 = -(float)(NS - 1) * 0.5f;
    const float F0 = fmaf(t0, fi,  f0);   // fast coord at k=0
    const float S0 = fmaf(t0, sli, s0);   // slow coord at k=0

    // Outer range: any nonzero contribution requires p in (-1, 512) both dims.
    float kloF, khiF, kloS, khiS;
    range1(F0, fi,  -1.002f, 512.002f, kloF, khiF);
    range1(S0, sli, -1.002f, 512.002f, kloS, khiS);
    const int kA = max(0,      (int)ceilf(fmaxf(kloF, kloS)));
    const int kB = min(NS - 1, (int)floorf(fminf(khiF, khiS)));

    // Interior range: whole 2x2 footprint in-bounds (p in [0, 511)).
    range1(F0, fi,  0.002f, 510.998f, kloF, khiF);
    range1(S0, sli, 0.002f, 510.998f, kloS, khiS);
    const int kC = max(kA, (int)ceilf(fmaxf(kloF, kloS)));
    const int kD = min(kB, (int)floorf(fminf(khiF, khiS)));

    auto edge_sample = [&](int k) -> float {
        const float kf = (float)k;
        const float pf = fmaf(kf, fi,  F0);
        const float ps = fmaf(kf, sli, S0);
        const float ff = floorf(pf), sf = floorf(ps);
        const float fx = pf - ff,   fy = ps - sf;
        const int xf = (int)ff, ys = (int)sf;
        auto tap = [&](int sr, int fc) -> float {
            if ((unsigned)sr < 512u && (unsigned)fc < 512u)
                return __half2float(base[sr * W + fc]);
            return 0.f;
        };
        const float v00 = tap(ys, xf),     v01 = tap(ys, xf + 1);
        const float v10 = tap(ys + 1, xf), v11 = tap(ys + 1, xf + 1);
        const float top = fmaf(fx, v01 - v00, v00);
        const float bot = fmaf(fx, v11 - v10, v10);
        return fmaf(fy, bot - top, top);
    };

    auto fast_sample = [&](int k) -> float {
        const float kf = (float)k;
        const float pf = fmaf(kf, fi,  F0);
        const float ps = fmaf(kf, sli, S0);
        const float ff = floorf(pf), sf = floorf(ps);
        const float fx = pf - ff,   fy = ps - sf;
        const int idx = (int)sf * W + (int)ff;
        const float v00 = __half2float(base[idx]);
        const float v01 = __half2float(base[idx + 1]);
        const float v10 = __half2float(base[idx + W]);
        const float v11 = __half2float(base[idx + W + 1]);
        const float top = fmaf(fx, v01 - v00, v00);
        const float bot = fmaf(fx, v11 - v10, v10);
        return fmaf(fy, bot - top, top);
    };

    float acc = 0.f;
    const int e1hi = (kC <= kD) ? kC - 1 : kB;
    for (int k = kA; k <= e1hi; ++k) acc += edge_sample(k);
    if (kC <= kD) {
        float a0 = 0.f, a1 = 0.f, a2 = 0.f, a3 = 0.f;
        int k = kC;
        for (; k + 3 <= kD; k += 4) {
            a0 += fast_sample(k);
            a1 += fast_sample(k + 1);
            a2 += fast_sample(k + 2);
            a3 += fast_sample(k + 3);
        }
        for (; k <= kD; ++k) a0 += fast_sample(k);
        acc += (a0 + a1) + (a2 + a3);
        for (int k2 = kD + 1; k2 <= kB; ++k2) acc += edge_sample(k2);
    }
    sino[a * ND + d] = acc;   // STEP = 1.0
}

// ---------------- fallback (tiny ws): fused fp32, no staging ----------------
__global__ __launch_bounds__(256) void proj_fused(const float* __restrict__ A,
                                                  const float* __restrict__ B,
                                                  const float* __restrict__ angles,
                                                  float* __restrict__ sino) {
    const int d = blockIdx.x * blockDim.x + threadIdx.x;
    const int a = blockIdx.y;
    if (d >= ND) return;
    float si, c;
    sincosf(angles[a], &si, &c);
    const float cx = (W - 1) * 0.5f, cy = (H - 1) * 0.5f;
    const float s  = (float)d - (ND - 1) * 0.5f;
    const float bx = fmaf(s, c, cx), by = fmaf(s, si, cy);
    const float t0 = -(float)(NS - 1) * 0.5f;
    float acc = 0.f;
    for (int k = 0; k < NS; ++k) {
        const float t = t0 + (float)k;
        const float px = fmaf(t, -si, bx), py = fmaf(t, c, by);
        const float x0f = floorf(px), y0f = floorf(py);
        const float fx = px - x0f, fy = py - y0f;
        const int ix = (int)x0f, iy = (int)y0f;
        auto tap = [&](int yi, int xi) -> float {
            if (xi < 0 || xi >= W || yi < 0 || yi >= H) return 0.f;
            return A[yi * W + xi] + B[yi * W + xi];
        };
        float v = 0.f;
        if (ix >= -1 && iy >= -1 && ix <= W - 1 && iy <= H - 1) {
            const float v00 = tap(iy, ix),     v01 = tap(iy, ix + 1);
            const float v10 = tap(iy + 1, ix), v11 = tap(iy + 1, ix + 1);
            const float top = fmaf(fx, v01 - v00, v00);
            const float bot = fmaf(fx, v11 - v10, v10);
            v = fmaf(fy, bot - top, top);
        }
        acc += v;
    }
    sino[a * ND + d] = acc;
}

__global__ void prep_copy(const float* __restrict__ reco, float* __restrict__ reco_out) {
    int i = blockIdx.x * blockDim.x + threadIdx.x;
    if (i < IMG_SIZE) reco_out[i] = reco[i];
}

extern "C" void kernel_launch(void* const* d_in, const int* in_sizes, int n_in,
                              void* d_out, int out_size, void* d_ws, size_t ws_size,
                              hipStream_t stream) {
    const float* x      = (const float*)d_in[0];
    const float* reco   = (const float*)d_in[1];
    const float* angles = (const float*)d_in[2];
    float* sino     = (float*)d_out;
    float* reco_out = sino + SINO_SIZE;

    const dim3 jb(256), jg((ND + 255) / 256, NA);
    const size_t need = 2 * (size_t)IMG_SIZE * sizeof(__half);

    if (ws_size >= need) {
        __half* img  = (__half*)d_ws;
        __half* imgT = img + IMG_SIZE;
        prep_stage<<<dim3(16, 16), dim3(32, 32), 0, stream>>>(x, reco, img, imgT, reco_out);
        proj_kernel<<<jg, jb, 0, stream>>>(img, imgT, angles, sino);
    } else {
        prep_copy<<<dim3((IMG_SIZE + 255) / 256), dim3(256), 0, stream>>>(reco, reco_out);
        proj_fused<<<jg, jb, 0, stream>>>(x, reco, angles, sino);
    }
}

// Round 3
// 260.863 us; speedup vs baseline: 2.0961x; 1.6310x over previous
//
#include <hip/hip_runtime.h>
#include <hip/hip_fp16.h>

// Radon forward projection (parallel beam), 512x512 image, 512 angles,
// 736 detectors x 736 samples, bilinear interpolation.
// Outputs (flat, concatenated): sino [1,512,736] then reco [1,512,512].
//
// R3: wave = 8 detectors x 8 interleaved samples (compact 2D footprint ->
//     ~3x fewer L1 line replays), pair-packed half2 image with zero-padded
//     border (2 dword loads/sample, zero bounds checks), shfl_xor reduction.

namespace {
constexpr int H = 512, W = 512, NA = 512, ND = 736, NS = 736;
constexpr int SINO_SIZE = NA * ND;
constexpr int IMG_SIZE = H * W;
constexpr int PW = 516;            // padded pair-row stride (half2 units)
constexpr int PH = 514;            // padded rows
constexpr int PAIR_SIZE = PH * PW; // half2 elements per orientation
}

// ---------- prep 1: fp16 img = x + reco, fp16 transposed copy, reco out ----
__global__ __launch_bounds__(1024) void prep_stage(const float* __restrict__ x,
                                                   const float* __restrict__ reco,
                                                   __half* __restrict__ img,
                                                   __half* __restrict__ imgT,
                                                   float* __restrict__ reco_out) {
    __shared__ float tile[32][33];
    const int tx = threadIdx.x, ty = threadIdx.y;
    const int col = blockIdx.x * 32 + tx;
    const int row = blockIdx.y * 32 + ty;
    const int i = row * W + col;
    const float r = reco[i];
    const float v = x[i] + r;
    reco_out[i] = r;
    img[i] = __float2half(v);
    tile[ty][tx] = v;
    __syncthreads();
    const int trow = blockIdx.x * 32 + ty;
    const int tcol = blockIdx.y * 32 + tx;
    imgT[trow * W + tcol] = __float2half(tile[tx][ty]);
}

// ---------- prep 2: zero-padded pair-packed layouts ------------------------
// P[ri][ci] = ( v(ri-1, ci-1), v(ri-1, ci) ), zero outside [0,512)^2.
__global__ __launch_bounds__(256) void prep_pairs(const __half* __restrict__ img,
                                                  const __half* __restrict__ imgT,
                                                  __half2* __restrict__ P,
                                                  __half2* __restrict__ PT) {
    const int ci = blockIdx.x * 64 + (threadIdx.x & 63);
    const int ri = blockIdx.y * 4 + (threadIdx.x >> 6);
    if (ci >= PH || ri >= PH) return;
    const int r = ri - 1, c0 = ci - 1, c1 = ci;
    const bool rok = (unsigned)r < 512u;
    const bool c0ok = rok && ((unsigned)c0 < 512u);
    const bool c1ok = rok && ((unsigned)c1 < 512u);
    const __half z = __float2half(0.f);
    __half2 a, b;
    a.x = c0ok ? img[r * W + c0] : z;
    a.y = c1ok ? img[r * W + c1] : z;
    b.x = c0ok ? imgT[r * W + c0] : z;
    b.y = c1ok ? imgT[r * W + c1] : z;
    P [ri * PW + ci] = a;
    PT[ri * PW + ci] = b;
}

// Per-dim k-range for p0 + k*inc in [lo, hi].
__device__ inline void range1(float p0, float inc, float lo, float hi,
                              float& klo, float& khi) {
    if (inc > 1e-6f)       { klo = (lo - p0) / inc; khi = (hi - p0) / inc; }
    else if (inc < -1e-6f) { klo = (hi - p0) / inc; khi = (lo - p0) / inc; }
    else if (p0 >= lo && p0 <= hi) { klo = -1e9f; khi = 1e9f; }
    else                   { klo = 1e9f;  khi = -1e9f; }
}

// Wave = 8 detectors (lane&7) x 8 k-chunks (lane>>3). Block 256 = 4 waves
// = 32 detectors. Grid (23, 512).
__global__ __launch_bounds__(256) void proj_kernel(const __half2* __restrict__ P,
                                                   const __half2* __restrict__ PT,
                                                   const float* __restrict__ angles,
                                                   float* __restrict__ sino) {
    const int lane = threadIdx.x & 63;
    const int ld = lane & 7;        // detector within group
    const int lk = lane >> 3;       // k interleave slot
    const int w  = threadIdx.x >> 6;
    const int d  = blockIdx.x * 32 + w * 8 + ld;
    const int a  = blockIdx.y;

    float si, c;
    sincosf(angles[a], &si, &c);

    const float cx = (W - 1) * 0.5f, cy = (H - 1) * 0.5f;
    const float s  = (float)d - (ND - 1) * 0.5f;
    const float bx = fmaf(s, c, cx);    // px = bx - t*si
    const float by = fmaf(s, si, cy);   // py = by + t*c

    // Orientation: fast dim = contiguous dim; pick layout where the
    // per-detector (lane) step along the contiguous dim is maximal.
    const __half2* base;
    float f0, fi, s0, sli;
    if (fabsf(c) >= fabsf(si)) { base = P;  f0 = bx; fi = -si; s0 = by; sli = c;   }
    else                       { base = PT; f0 = by; fi = c;   s0 = bx; sli = -si; }

    const float t0 = -(float)(NS - 1) * 0.5f;
    const float F0 = fmaf(t0, fi,  f0);
    const float S0 = fmaf(t0, sli, s0);

    // Clip to coords in (-1, 512) both dims (padded array covers the rest).
    float kloF, khiF, kloS, khiS;
    range1(F0, fi,  -0.998f, 511.998f, kloF, khiF);
    range1(S0, sli, -0.998f, 511.998f, kloS, khiS);
    const int kA = max(0,      (int)ceilf(fmaxf(kloF, kloS)));
    const int kB = min(NS - 1, (int)floorf(fminf(khiF, khiS)));

    float acc = 0.f;
    #pragma unroll 4
    for (int k = kA + lk; k <= kB; k += 8) {
        const float kf = (float)k;
        const float pf = fmaf(kf, fi,  F0);
        const float ps = fmaf(kf, sli, S0);
        const float ff = floorf(pf), sf = floorf(ps);
        const float fx = pf - ff,   fy = ps - sf;
        const int idx = ((int)sf + 1) * PW + ((int)ff + 1);
        const float2 A = __half22float2(base[idx]);        // v00, v01
        const float2 B = __half22float2(base[idx + PW]);   // v10, v11
        const float top = fmaf(fx, A.y - A.x, A.x);
        const float bot = fmaf(fx, B.y - B.x, B.x);
        acc += fmaf(fy, bot - top, top);
    }

    // Sum the 8 lk slots of each detector (lanes differing in bits 3..5).
    acc += __shfl_xor(acc, 8);
    acc += __shfl_xor(acc, 16);
    acc += __shfl_xor(acc, 32);
    if (lk == 0 && d < ND) sino[a * ND + d] = acc;   // STEP = 1.0
}

// ---------------- fallbacks (small ws) --------------------------------------
__global__ __launch_bounds__(256) void proj_r2(const __half* __restrict__ img,
                                               const __half* __restrict__ imgT,
                                               const float* __restrict__ angles,
                                               float* __restrict__ sino) {
    const int d = blockIdx.x * blockDim.x + threadIdx.x;
    const int a = blockIdx.y;
    if (d >= ND) return;
    float si, c;
    sincosf(angles[a], &si, &c);
    const float cx = (W - 1) * 0.5f, cy = (H - 1) * 0.5f;
    const float s  = (float)d - (ND - 1) * 0.5f;
    const float bx = fmaf(s, c, cx), by = fmaf(s, si, cy);
    const __half* base;
    float f0, fi, s0, sli;
    if (fabsf(c) >= fabsf(si)) { base = img;  f0 = bx; fi = -si; s0 = by; sli = c;  }
    else                       { base = imgT; f0 = by; fi = c;   s0 = bx; sli = -si; }
    const float t0 = -(float)(NS - 1) * 0.5f;
    const float F0 = fmaf(t0, fi,  f0);
    const float S0 = fmaf(t0, sli, s0);
    float kloF, khiF, kloS, khiS;
    range1(F0, fi,  -1.002f, 512.002f, kloF, khiF);
    range1(S0, sli, -1.002f, 512.002f, kloS, khiS);
    const int kA = max(0,      (int)ceilf(fmaxf(kloF, kloS)));
    const int kB = min(NS - 1, (int)floorf(fminf(khiF, khiS)));
    float acc = 0.f;
    for (int k = kA; k <= kB; ++k) {
        const float kf = (float)k;
        const float pf = fmaf(kf, fi,  F0);
        const float ps = fmaf(kf, sli, S0);
        const float ff = floorf(pf), sf = floorf(ps);
        const float fx = pf - ff,   fy = ps - sf;
        const int xf = (int)ff, ys = (int)sf;
        auto tap = [&](int sr, int fc) -> float {
            if ((unsigned)sr < 512u && (unsigned)fc < 512u)
                return __half2float(base[sr * W + fc]);
            return 0.f;
        };
        const float v00 = tap(ys, xf),     v01 = tap(ys, xf + 1);
        const float v10 = tap(ys + 1, xf), v11 = tap(ys + 1, xf + 1);
        const float top = fmaf(fx, v01 - v00, v00);
        const float bot = fmaf(fx, v11 - v10, v10);
        acc += fmaf(fy, bot - top, top);
    }
    sino[a * ND + d] = acc;
}

__global__ __launch_bounds__(256) void proj_fused(const float* __restrict__ A,
                                                  const float* __restrict__ B,
                                                  const float* __restrict__ angles,
                                                  float* __restrict__ sino) {
    const int d = blockIdx.x * blockDim.x + threadIdx.x;
    const int a = blockIdx.y;
    if (d >= ND) return;
    float si, c;
    sincosf(angles[a], &si, &c);
    const float cx = (W - 1) * 0.5f, cy = (H - 1) * 0.5f;
    const float s  = (float)d - (ND - 1) * 0.5f;
    const float bx = fmaf(s, c, cx), by = fmaf(s, si, cy);
    const float t0 = -(float)(NS - 1) * 0.5f;
    float acc = 0.f;
    for (int k = 0; k < NS; ++k) {
        const float t = t0 + (float)k;
        const float px = fmaf(t, -si, bx), py = fmaf(t, c, by);
        const float x0f = floorf(px), y0f = floorf(py);
        const float fx = px - x0f, fy = py - y0f;
        const int ix = (int)x0f, iy = (int)y0f;
        auto tap = [&](int yi, int xi) -> float {
            if (xi < 0 || xi >= W || yi < 0 || yi >= H) return 0.f;
            return A[yi * W + xi] + B[yi * W + xi];
        };
        float v = 0.f;
        if (ix >= -1 && iy >= -1 && ix <= W - 1 && iy <= H - 1) {
            const float v00 = tap(iy, ix),     v01 = tap(iy, ix + 1);
            const float v10 = tap(iy + 1, ix), v11 = tap(iy + 1, ix + 1);
            const float top = fmaf(fx, v01 - v00, v00);
            const float bot = fmaf(fx, v11 - v10, v10);
            v = fmaf(fy, bot - top, top);
        }
        acc += v;
    }
    sino[a * ND + d] = acc;
}

__global__ void prep_copy(const float* __restrict__ reco, float* __restrict__ reco_out) {
    int i = blockIdx.x * blockDim.x + threadIdx.x;
    if (i < IMG_SIZE) reco_out[i] = reco[i];
}

extern "C" void kernel_launch(void* const* d_in, const int* in_sizes, int n_in,
                              void* d_out, int out_size, void* d_ws, size_t ws_size,
                              hipStream_t stream) {
    const float* x      = (const float*)d_in[0];
    const float* reco   = (const float*)d_in[1];
    const float* angles = (const float*)d_in[2];
    float* sino     = (float*)d_out;
    float* reco_out = sino + SINO_SIZE;

    const size_t need_imgs  = 2 * (size_t)IMG_SIZE * sizeof(__half);           // 1 MiB
    const size_t need_pairs = 2 * (size_t)PAIR_SIZE * sizeof(__half2);         // ~2.02 MiB
    const size_t need_full  = need_imgs + need_pairs;

    if (ws_size >= need_full) {
        __half*  img  = (__half*)d_ws;
        __half*  imgT = img + IMG_SIZE;
        __half2* P    = (__half2*)(imgT + IMG_SIZE);
        __half2* PT   = P + PAIR_SIZE;
        prep_stage<<<dim3(16, 16), dim3(32, 32), 0, stream>>>(x, reco, img, imgT, reco_out);
        prep_pairs<<<dim3((PH + 63) / 64, (PH + 3) / 4), dim3(256), 0, stream>>>(img, imgT, P, PT);
        proj_kernel<<<dim3((ND + 31) / 32, NA), dim3(256), 0, stream>>>(P, PT, angles, sino);
    } else if (ws_size >= need_imgs) {
        __half* img  = (__half*)d_ws;
        __half* imgT = img + IMG_SIZE;
        prep_stage<<<dim3(16, 16), dim3(32, 32), 0, stream>>>(x, reco, img, imgT, reco_out);
        proj_r2<<<dim3((ND + 255) / 256, NA), dim3(256), 0, stream>>>(img, imgT, angles, sino);
    } else {
        prep_copy<<<dim3((IMG_SIZE + 255) / 256), dim3(256), 0, stream>>>(reco, reco_out);
        proj_fused<<<dim3((ND + 255) / 256, NA), dim3(256), 0, stream>>>(x, reco, angles, sino);
    }
}